// Round 16
// baseline (89.045 us; speedup 1.0000x reference)
//
#include <hip/hip_runtime.h>

typedef unsigned short ushort_t;
typedef unsigned int uint32;

typedef __bf16 bf16x8 __attribute__((ext_vector_type(8)));
typedef float f32x4 __attribute__((ext_vector_type(4)));

// ---------- helpers ----------
__device__ __forceinline__ uint32 f2bf1(float f) {
  uint32 b = __float_as_uint(f);
  return (b + 0x7FFFu + ((b >> 16) & 1u)) >> 16;  // RNE
}
__device__ __forceinline__ uint32 packbf2(float a, float b) {
  return f2bf1(a) | (f2bf1(b) << 16);
}
__device__ __forceinline__ float bflo(uint32 u) { return __uint_as_float(u << 16); }
__device__ __forceinline__ float bfhi(uint32 u) { return __uint_as_float(u & 0xFFFF0000u); }

__device__ __forceinline__ void gload16(const void* g, void* l) {
  __builtin_amdgcn_global_load_lds(
      (const __attribute__((address_space(1))) unsigned int*)g,
      (__attribute__((address_space(3))) unsigned int*)l, 16, 0, 0);
}

// ---------- prep: weight transposes only (x is consumed fp32 by the GEMM) ---
__global__ __launch_bounds__(256) void prep_weights(
    const float* __restrict__ Wqkv, ushort_t* __restrict__ wqkvT,
    const float* __restrict__ Wproj, ushort_t* __restrict__ wprT) {
  const int bx = blockIdx.x;            // 4096 blocks: 128 x 32
  const int tid = threadIdx.x;
  const int gx = bx & 127, gy = bx >> 7;
  __shared__ float tile[32][33];
  const int tx = tid & 31, ty = tid >> 5;
  const float* src;
  ushort_t* dst;
  int Cc, c0;
  if (gx < 96) { src = Wqkv;  dst = wqkvT; Cc = 3072; c0 = gx << 5; }
  else         { src = Wproj; dst = wprT;  Cc = 1024; c0 = (gx - 96) << 5; }
  const int r0 = gy << 5;  // R = 1024
#pragma unroll
  for (int i = 0; i < 4; ++i)
    tile[ty + i * 8][tx] = src[(size_t)(r0 + ty + i * 8) * Cc + c0 + tx];
  __syncthreads();
#pragma unroll
  for (int i = 0; i < 4; ++i)
    dst[(size_t)(c0 + ty + i * 8) * 1024 + r0 + tx] = (ushort_t)f2bf1(tile[tx][ty + i * 8]);
}

// ============== 2-phase double-buffered bf16 GEMM (session-best core) ======
// C[M][Nn] = A[M][K] * Bt[Nn][K]^T (+bias).  BK=32, 4 waves (2x2).
// LDS: [2 bufs][rows][32] bf16 row-major; chunk slot s holds global chunk
// s ^ ((row>>1)&3)  (involution on BOTH stage-source and read; ~0 conflicts).
// A_F32 path: A is fp32 in HBM; staging = global fp32x4 loads (issued at
// loop top) -> packbf2 -> ds_write_b128 AFTER the MFMA block (T14 split:
// HBM latency hides under compute).  The ds_write targets the same bytes
// gload_lds would write (wvb + lane*16B == (row*32 + s*8) elems).
// Loop: STAGE(next buf) -> ds_read cur -> MFMA -> [A-cvt-writes] ->
// __syncthreads -> swap.  + T1 XCD-aware chunked block swizzle.

template <int ROWS>
__device__ __forceinline__ void stage2(ushort_t* dst, const ushort_t* gbase,
                                       int ldK, int tid) {
  const int r = tid >> 2, s = tid & 3;
  const int c = ((s ^ ((r >> 1) & 3)) << 3);    // pre-swizzled source chunk
  const int wvb = (tid >> 6) << 9;              // wave*512 elems (uniform dest)
  const ushort_t* g = gbase + (size_t)r * ldK + c;
  gload16(g, dst + wvb);
  if (ROWS == 128) gload16(g + (size_t)64 * ldK, dst + 2048 + wvb);
}

template <bool OUT_BF16, bool A_F32, int MF, int NF>
__global__ __launch_bounds__(256) void gemm2p(
    const void* __restrict__ Av, const ushort_t* __restrict__ Bt,
    void* __restrict__ Cout, const float* __restrict__ bias,
    const int M, const int Nn, const int K) {
  constexpr int BM = MF * 32, BN = NF * 32;
  constexpr int AL = BM * 32, BL = BN * 32;   // elems per buffer
  __shared__ ushort_t lA[2 * AL];
  __shared__ ushort_t lB[2 * BL];
  const int tid = threadIdx.x;
  const int lane = tid & 63, wave = tid >> 6;
  const int wm = wave >> 1, wn = wave & 1;

  // T1: XCD-aware chunked swizzle of the linear block id (nwg % 8 == 0).
  const int nwg = gridDim.x * gridDim.y;
  const int wg0 = blockIdx.y * gridDim.x + blockIdx.x;
  const int q8 = nwg >> 3;
  const int wg = (wg0 & 7) * q8 + (wg0 >> 3);
  const int bm = (wg / gridDim.x) * BM;
  const int bn = (wg % gridDim.x) * BN;

  const int l15 = lane & 15, l16 = lane >> 4;
  const int cK = ((l16 ^ ((l15 >> 1) & 3)) << 3);  // swizzled read chunk

  // staging geometry (shared by both A paths and B)
  const int sr = tid >> 2, ss = tid & 3;
  const int sc = ((ss ^ ((sr >> 1) & 3)) << 3);    // source chunk, elems
  const int wvb = (tid >> 6) << 9;

  const ushort_t* gA16 = A_F32 ? nullptr : (const ushort_t*)Av + (size_t)bm * K;
  const float*    gA32 = A_F32 ? (const float*)Av + (size_t)bm * K : nullptr;
  const ushort_t* gB = Bt + (size_t)bn * K;

  f32x4 acc[MF][NF] = {};

  // ---- prologue: stage tile 0 into buf 0 ----
  if constexpr (A_F32) {
    const float* g = gA32 + (size_t)sr * K + sc;
    float4 u0 = *(const float4*)g;
    float4 u1 = *(const float4*)(g + 4);
    uint4 w;
    w.x = packbf2(u0.x, u0.y); w.y = packbf2(u0.z, u0.w);
    w.z = packbf2(u1.x, u1.y); w.w = packbf2(u1.z, u1.w);
    *(uint4*)&lA[wvb + lane * 8] = w;
    if (BM == 128) {
      const float* g2 = g + (size_t)64 * K;
      float4 v0 = *(const float4*)g2;
      float4 v1 = *(const float4*)(g2 + 4);
      uint4 w2;
      w2.x = packbf2(v0.x, v0.y); w2.y = packbf2(v0.z, v0.w);
      w2.z = packbf2(v1.x, v1.y); w2.w = packbf2(v1.z, v1.w);
      *(uint4*)&lA[2048 + wvb + lane * 8] = w2;
    }
  } else {
    stage2<BM>(lA, gA16, K, tid);
  }
  stage2<BN>(lB, gB, K, tid);
  __syncthreads();

  int buf = 0;
  for (int k0 = 0; k0 < K; k0 += 32) {
    const bool nk = (k0 + 32) < K;
    // issue next-tile loads first
    float4 u0, u1, v0, v1;
    if (nk) {
      if constexpr (A_F32) {
        const float* g = gA32 + (size_t)sr * K + k0 + 32 + sc;
        u0 = *(const float4*)g;
        u1 = *(const float4*)(g + 4);
        if (BM == 128) {
          const float* g2 = g + (size_t)64 * K;
          v0 = *(const float4*)g2;
          v1 = *(const float4*)(g2 + 4);
        }
      } else {
        stage2<BM>(lA + (buf ^ 1) * AL, gA16 + k0 + 32, K, tid);
      }
      stage2<BN>(lB + (buf ^ 1) * BL, gB + k0 + 32, K, tid);
    }
    // read fragments from current buffer
    bf16x8 a[MF], b[NF];
#pragma unroll
    for (int m = 0; m < MF; ++m)
      a[m] = *(const bf16x8*)&lA[buf * AL + ((wm * MF + m) * 16 + l15) * 32 + cK];
#pragma unroll
    for (int n = 0; n < NF; ++n)
      b[n] = *(const bf16x8*)&lB[buf * BL + ((wn * NF + n) * 16 + l15) * 32 + cK];
#pragma unroll
    for (int m = 0; m < MF; ++m)
#pragma unroll
      for (int n = 0; n < NF; ++n)
        acc[m][n] = __builtin_amdgcn_mfma_f32_16x16x32_bf16(a[m], b[n], acc[m][n], 0, 0, 0);
    // A cvt + LDS write AFTER compute (loads landed during MFMA)
    if (nk) {
      if constexpr (A_F32) {
        ushort_t* dst = lA + (buf ^ 1) * AL;
        uint4 w;
        w.x = packbf2(u0.x, u0.y); w.y = packbf2(u0.z, u0.w);
        w.z = packbf2(u1.x, u1.y); w.w = packbf2(u1.z, u1.w);
        *(uint4*)&dst[wvb + lane * 8] = w;
        if (BM == 128) {
          uint4 w2;
          w2.x = packbf2(v0.x, v0.y); w2.y = packbf2(v0.z, v0.w);
          w2.z = packbf2(v1.x, v1.y); w2.w = packbf2(v1.z, v1.w);
          *(uint4*)&dst[2048 + wvb + lane * 8] = w2;
        }
      }
    }
    __syncthreads();  // drains gload_lds + ds_writes; next buf ready
    buf ^= 1;
  }

  // epilogue: C/D layout col=lane&15, row=(lane>>4)*4+reg  [m89/m91 verified]
  const int r0 = bm + wm * (MF * 16) + (l16 << 2);
  const int c0 = bn + wn * (NF * 16) + l15;
#pragma unroll
  for (int m = 0; m < MF; ++m)
#pragma unroll
    for (int n = 0; n < NF; ++n)
#pragma unroll
      for (int j = 0; j < 4; ++j) {
        const int row = r0 + m * 16 + j;
        const int col = c0 + n * 16;
        if (OUT_BF16)
          ((ushort_t*)Cout)[(size_t)row * Nn + col] = (ushort_t)f2bf1(acc[m][n][j]);
        else
          ((float*)Cout)[(size_t)row * Nn + col] = acc[m][n][j] + bias[col];
      }
}

// ---------- banded attention ----------
__global__ __launch_bounds__(256) void attn_band(
    const ushort_t* __restrict__ qkv, ushort_t* __restrict__ aout) {
  __shared__ float Ks[80 * 68];
  __shared__ float Vs[80 * 68];
  const int tid = threadIdx.x;
  const int i0 = blockIdx.x << 6;
  const int h = blockIdx.y;
  const int b = blockIdx.z;
  const size_t rowbase = (size_t)b * 2048;

  for (int idx = tid; idx < 1280; idx += 256) {
    const int t = idx >> 4, c = idx & 15;
    const int j = i0 - 8 + t;
    float k0 = 0.f, k1 = 0.f, k2 = 0.f, k3 = 0.f;
    float v0 = 0.f, v1 = 0.f, v2 = 0.f, v3 = 0.f;
    if ((unsigned)j < 2048u) {
      const ushort_t* p = qkv + (rowbase + j) * 3072 + (h << 6) + (c << 2);
      uint2 rk = *(const uint2*)(p + 1024);
      uint2 rv = *(const uint2*)(p + 2048);
      k0 = bflo(rk.x); k1 = bfhi(rk.x); k2 = bflo(rk.y); k3 = bfhi(rk.y);
      v0 = bflo(rv.x); v1 = bfhi(rv.x); v2 = bflo(rv.y); v3 = bfhi(rv.y);
    }
    *(float4*)&Ks[t * 68 + (c << 2)] = make_float4(k0, k1, k2, k3);
    *(float4*)&Vs[t * 68 + (c << 2)] = make_float4(v0, v1, v2, v3);
  }
  __syncthreads();

  const int lane = tid & 63, wv = tid >> 6;
  const int qs = lane >> 2, dg = lane & 3;
  const int qi = (wv << 4) + qs;
  const int i = i0 + qi;

  const ushort_t* qp = qkv + (rowbase + i) * 3072 + (h << 6) + (dg << 4);
  float q[16];
  {
    uint4 u0 = *(const uint4*)qp;
    uint4 u1 = *(const uint4*)(qp + 8);
    q[0] = bflo(u0.x); q[1] = bfhi(u0.x); q[2] = bflo(u0.y); q[3] = bfhi(u0.y);
    q[4] = bflo(u0.z); q[5] = bfhi(u0.z); q[6] = bflo(u0.w); q[7] = bfhi(u0.w);
    q[8] = bflo(u1.x); q[9] = bfhi(u1.x); q[10] = bflo(u1.y); q[11] = bfhi(u1.y);
    q[12] = bflo(u1.z); q[13] = bfhi(u1.z); q[14] = bflo(u1.w); q[15] = bfhi(u1.w);
  }

  float s[17];
#pragma unroll
  for (int jo = 0; jo < 17; ++jo) {
    const float* kr = &Ks[(qi + jo) * 68 + (dg << 4)];
    float d = 0.f;
#pragma unroll
    for (int c = 0; c < 4; ++c) {
      float4 kv = *(const float4*)(kr + (c << 2));
      d += q[c * 4 + 0] * kv.x + q[c * 4 + 1] * kv.y +
           q[c * 4 + 2] * kv.z + q[c * 4 + 3] * kv.w;
    }
    d += __shfl_xor(d, 1);
    d += __shfl_xor(d, 2);
    const int jg = i - 8 + jo;
    s[jo] = ((unsigned)jg < 2048u) ? d * 0.125f : -1e30f;
  }
  float m = s[0];
#pragma unroll
  for (int jo = 1; jo < 17; ++jo) m = fmaxf(m, s[jo]);
  float sum = 0.f;
#pragma unroll
  for (int jo = 0; jo < 17; ++jo) {
    s[jo] = __expf(s[jo] - m);
    sum += s[jo];
  }
  const float inv = 1.f / sum;

  float o[16];
#pragma unroll
  for (int dd = 0; dd < 16; ++dd) o[dd] = 0.f;
#pragma unroll
  for (int jo = 0; jo < 17; ++jo) {
    const float* vr = &Vs[(qi + jo) * 68 + (dg << 4)];
    const float w = s[jo];
#pragma unroll
    for (int c = 0; c < 4; ++c) {
      float4 vv = *(const float4*)(vr + (c << 2));
      o[c * 4 + 0] += w * vv.x; o[c * 4 + 1] += w * vv.y;
      o[c * 4 + 2] += w * vv.z; o[c * 4 + 3] += w * vv.w;
    }
  }

  ushort_t* op = aout + (rowbase + i) * 1024 + (h << 6) + (dg << 4);
  uint4 w0, w1;
  w0.x = packbf2(o[0] * inv, o[1] * inv);
  w0.y = packbf2(o[2] * inv, o[3] * inv);
  w0.z = packbf2(o[4] * inv, o[5] * inv);
  w0.w = packbf2(o[6] * inv, o[7] * inv);
  w1.x = packbf2(o[8] * inv, o[9] * inv);
  w1.y = packbf2(o[10] * inv, o[11] * inv);
  w1.z = packbf2(o[12] * inv, o[13] * inv);
  w1.w = packbf2(o[14] * inv, o[15] * inv);
  *(uint4*)op = w0;
  *(uint4*)(op + 8) = w1;
}

// ---------- launch ----------
extern "C" void kernel_launch(void* const* d_in, const int* in_sizes, int n_in,
                              void* d_out, int out_size, void* d_ws, size_t ws_size,
                              hipStream_t stream) {
  const float* x = (const float*)d_in[0];
  const float* Wqkv = (const float*)d_in[1];
  const float* Wproj = (const float*)d_in[2];
  const float* bproj = (const float*)d_in[3];
  float* out = (float*)d_out;

  char* ws = (char*)d_ws;
  ushort_t* wqkvT = (ushort_t*)(ws + (8u << 20));
  ushort_t* wprT  = (ushort_t*)(ws + (14u << 20));
  ushort_t* qkv   = (ushort_t*)(ws + (16u << 20));
  ushort_t* aoutb = (ushort_t*)(ws + (40u << 20));

  prep_weights<<<4096, 256, 0, stream>>>(Wqkv, wqkvT, Wproj, wprT);
  // QKV: 128x128 tile, A = x fp32 (fused cvt), grid 24x32 = 768 blocks
  gemm2p<true, true, 4, 4><<<dim3(24, 32), 256, 0, stream>>>(
      x, wqkvT, qkv, nullptr, 4096, 3072, 1024);
  attn_band<<<dim3(32, 16, 2), 256, 0, stream>>>(qkv, aoutb);
  // proj: 64x128 tile, A = attn out bf16, grid 8x64 = 512 blocks
  gemm2p<false, false, 2, 4><<<dim3(8, 64), 256, 0, stream>>>(
      aoutb, wprT, out, bproj, 4096, 1024, 1024);
}

// Round 17
// 81.660 us; speedup vs baseline: 1.0904x; 1.0904x over previous
//
#include <hip/hip_runtime.h>

typedef unsigned short ushort_t;
typedef unsigned int uint32;

typedef __bf16 bf16x8 __attribute__((ext_vector_type(8)));
typedef float f32x4 __attribute__((ext_vector_type(4)));

// ---------- helpers ----------
__device__ __forceinline__ uint32 f2bf1(float f) {
  uint32 b = __float_as_uint(f);
  return (b + 0x7FFFu + ((b >> 16) & 1u)) >> 16;  // RNE
}
__device__ __forceinline__ uint32 packbf2(float a, float b) {
  return f2bf1(a) | (f2bf1(b) << 16);
}
__device__ __forceinline__ float bflo(uint32 u) { return __uint_as_float(u << 16); }
__device__ __forceinline__ float bfhi(uint32 u) { return __uint_as_float(u & 0xFFFF0000u); }

__device__ __forceinline__ void gload16(const void* g, void* l) {
  __builtin_amdgcn_global_load_lds(
      (const __attribute__((address_space(1))) unsigned int*)g,
      (__attribute__((address_space(3))) unsigned int*)l, 16, 0, 0);
}

// ---------- fused prep: x cvt (blocks 0..4095) + weight transposes ----------
__global__ __launch_bounds__(256) void prep_inputs(
    const float* __restrict__ x, ushort_t* __restrict__ xb,
    const float* __restrict__ Wqkv, ushort_t* __restrict__ wqkvT,
    const float* __restrict__ Wproj, ushort_t* __restrict__ wprT) {
  int bx = blockIdx.x;
  const int tid = threadIdx.x;
  if (bx < 4096) {
    const int i = bx * 256 + tid;  // 1048576 float4's
    float4 v = ((const float4*)x)[i];
    uint2 r;
    r.x = packbf2(v.x, v.y);
    r.y = packbf2(v.z, v.w);
    ((uint2*)xb)[i] = r;
    return;
  }
  bx -= 4096;                       // 4096 transpose blocks: 128 x 32
  const int gx = bx & 127, gy = bx >> 7;
  __shared__ float tile[32][33];
  const int tx = tid & 31, ty = tid >> 5;
  const float* src;
  ushort_t* dst;
  int Cc, c0;
  if (gx < 96) { src = Wqkv;  dst = wqkvT; Cc = 3072; c0 = gx << 5; }
  else         { src = Wproj; dst = wprT;  Cc = 1024; c0 = (gx - 96) << 5; }
  const int r0 = gy << 5;  // R = 1024
#pragma unroll
  for (int i = 0; i < 4; ++i)
    tile[ty + i * 8][tx] = src[(size_t)(r0 + ty + i * 8) * Cc + c0 + tx];
  __syncthreads();
#pragma unroll
  for (int i = 0; i < 4; ++i)
    dst[(size_t)(c0 + ty + i * 8) * 1024 + r0 + tx] = (ushort_t)f2bf1(tile[tx][ty + i * 8]);
}

// ============== 2-phase double-buffered bf16 GEMM (session best) ===========
// C[M][Nn] = A[M][K] * Bt[Nn][K]^T (+bias).  BK=32, 4 waves (2x2).
// Per-wave output (MF*16) x (NF*16); block tile BM=2*MF*16, BN=2*NF*16.
// LDS: [2 bufs][rows][32] bf16 row-major; chunk slot s holds global chunk
// s ^ ((row>>1)&3)  (involution applied on BOTH stage-source and read;
// measured ~0 bank conflicts).
// Loop: STAGE(next buf) -> ds_read cur -> MFMA -> __syncthreads -> swap.
// + T1 XCD-aware chunked block swizzle (grid size % 8 == 0).

template <int ROWS>
__device__ __forceinline__ void stage2(ushort_t* dst, const ushort_t* gbase,
                                       int ldK, int tid) {
  const int r = tid >> 2, s = tid & 3;
  const int c = ((s ^ ((r >> 1) & 3)) << 3);    // pre-swizzled source chunk
  const int wvb = (tid >> 6) << 9;              // wave*512 elems (uniform dest)
  const ushort_t* g = gbase + (size_t)r * ldK + c;
  gload16(g, dst + wvb);
  if (ROWS == 128) gload16(g + (size_t)64 * ldK, dst + 2048 + wvb);
}

template <bool OUT_BF16, int MF, int NF>
__global__ __launch_bounds__(256) void gemm2p(
    const ushort_t* __restrict__ A, const ushort_t* __restrict__ Bt,
    void* __restrict__ Cout, const float* __restrict__ bias,
    const int M, const int Nn, const int K) {
  constexpr int BM = MF * 32, BN = NF * 32;
  constexpr int AL = BM * 32, BL = BN * 32;   // elems per buffer
  __shared__ ushort_t lA[2 * AL];
  __shared__ ushort_t lB[2 * BL];
  const int tid = threadIdx.x;
  const int lane = tid & 63, wave = tid >> 6;
  const int wm = wave >> 1, wn = wave & 1;

  // T1: XCD-aware chunked swizzle of the linear block id (nwg % 8 == 0).
  const int nwg = gridDim.x * gridDim.y;
  const int wg0 = blockIdx.y * gridDim.x + blockIdx.x;
  const int q8 = nwg >> 3;
  const int wg = (wg0 & 7) * q8 + (wg0 >> 3);
  const int bm = (wg / gridDim.x) * BM;
  const int bn = (wg % gridDim.x) * BN;

  const int l15 = lane & 15, l16 = lane >> 4;
  const int cK = ((l16 ^ ((l15 >> 1) & 3)) << 3);  // swizzled read chunk

  const ushort_t* gA = A + (size_t)bm * K;
  const ushort_t* gB = Bt + (size_t)bn * K;

  f32x4 acc[MF][NF] = {};

  // prologue: stage tile 0 into buf 0
  stage2<BM>(lA, gA, K, tid);
  stage2<BN>(lB, gB, K, tid);
  __syncthreads();

  int buf = 0;
  for (int k0 = 0; k0 < K; k0 += 32) {
    // issue next-tile stages first (land by this iter's closing barrier)
    if (k0 + 32 < K) {
      stage2<BM>(lA + (buf ^ 1) * AL, gA + k0 + 32, K, tid);
      stage2<BN>(lB + (buf ^ 1) * BL, gB + k0 + 32, K, tid);
    }
    // read fragments from current buffer
    bf16x8 a[MF], b[NF];
#pragma unroll
    for (int m = 0; m < MF; ++m)
      a[m] = *(const bf16x8*)&lA[buf * AL + ((wm * MF + m) * 16 + l15) * 32 + cK];
#pragma unroll
    for (int n = 0; n < NF; ++n)
      b[n] = *(const bf16x8*)&lB[buf * BL + ((wn * NF + n) * 16 + l15) * 32 + cK];
#pragma unroll
    for (int m = 0; m < MF; ++m)
#pragma unroll
      for (int n = 0; n < NF; ++n)
        acc[m][n] = __builtin_amdgcn_mfma_f32_16x16x32_bf16(a[m], b[n], acc[m][n], 0, 0, 0);
    __syncthreads();  // vmcnt(0) drain + barrier: next buf ready, cur buf free
    buf ^= 1;
  }

  // epilogue: C/D layout col=lane&15, row=(lane>>4)*4+reg  [m89/m91 verified]
  const int r0 = bm + wm * (MF * 16) + (l16 << 2);
  const int c0 = bn + wn * (NF * 16) + l15;
#pragma unroll
  for (int m = 0; m < MF; ++m)
#pragma unroll
    for (int n = 0; n < NF; ++n)
#pragma unroll
      for (int j = 0; j < 4; ++j) {
        const int row = r0 + m * 16 + j;
        const int col = c0 + n * 16;
        if (OUT_BF16)
          ((ushort_t*)Cout)[(size_t)row * Nn + col] = (ushort_t)f2bf1(acc[m][n][j]);
        else
          ((float*)Cout)[(size_t)row * Nn + col] = acc[m][n][j] + bias[col];
      }
}

// ---------- banded attention ----------
__global__ __launch_bounds__(256) void attn_band(
    const ushort_t* __restrict__ qkv, ushort_t* __restrict__ aout) {
  __shared__ float Ks[80 * 68];
  __shared__ float Vs[80 * 68];
  const int tid = threadIdx.x;
  const int i0 = blockIdx.x << 6;
  const int h = blockIdx.y;
  const int b = blockIdx.z;
  const size_t rowbase = (size_t)b * 2048;

  for (int idx = tid; idx < 1280; idx += 256) {
    const int t = idx >> 4, c = idx & 15;
    const int j = i0 - 8 + t;
    float k0 = 0.f, k1 = 0.f, k2 = 0.f, k3 = 0.f;
    float v0 = 0.f, v1 = 0.f, v2 = 0.f, v3 = 0.f;
    if ((unsigned)j < 2048u) {
      const ushort_t* p = qkv + (rowbase + j) * 3072 + (h << 6) + (c << 2);
      uint2 rk = *(const uint2*)(p + 1024);
      uint2 rv = *(const uint2*)(p + 2048);
      k0 = bflo(rk.x); k1 = bfhi(rk.x); k2 = bflo(rk.y); k3 = bfhi(rk.y);
      v0 = bflo(rv.x); v1 = bfhi(rv.x); v2 = bflo(rv.y); v3 = bfhi(rv.y);
    }
    *(float4*)&Ks[t * 68 + (c << 2)] = make_float4(k0, k1, k2, k3);
    *(float4*)&Vs[t * 68 + (c << 2)] = make_float4(v0, v1, v2, v3);
  }
  __syncthreads();

  const int lane = tid & 63, wv = tid >> 6;
  const int qs = lane >> 2, dg = lane & 3;
  const int qi = (wv << 4) + qs;
  const int i = i0 + qi;

  const ushort_t* qp = qkv + (rowbase + i) * 3072 + (h << 6) + (dg << 4);
  float q[16];
  {
    uint4 u0 = *(const uint4*)qp;
    uint4 u1 = *(const uint4*)(qp + 8);
    q[0] = bflo(u0.x); q[1] = bfhi(u0.x); q[2] = bflo(u0.y); q[3] = bfhi(u0.y);
    q[4] = bflo(u0.z); q[5] = bfhi(u0.z); q[6] = bflo(u0.w); q[7] = bfhi(u0.w);
    q[8] = bflo(u1.x); q[9] = bfhi(u1.x); q[10] = bflo(u1.y); q[11] = bfhi(u1.y);
    q[12] = bflo(u1.z); q[13] = bfhi(u1.z); q[14] = bflo(u1.w); q[15] = bfhi(u1.w);
  }

  float s[17];
#pragma unroll
  for (int jo = 0; jo < 17; ++jo) {
    const float* kr = &Ks[(qi + jo) * 68 + (dg << 4)];
    float d = 0.f;
#pragma unroll
    for (int c = 0; c < 4; ++c) {
      float4 kv = *(const float4*)(kr + (c << 2));
      d += q[c * 4 + 0] * kv.x + q[c * 4 + 1] * kv.y +
           q[c * 4 + 2] * kv.z + q[c * 4 + 3] * kv.w;
    }
    d += __shfl_xor(d, 1);
    d += __shfl_xor(d, 2);
    const int jg = i - 8 + jo;
    s[jo] = ((unsigned)jg < 2048u) ? d * 0.125f : -1e30f;
  }
  float m = s[0];
#pragma unroll
  for (int jo = 1; jo < 17; ++jo) m = fmaxf(m, s[jo]);
  float sum = 0.f;
#pragma unroll
  for (int jo = 0; jo < 17; ++jo) {
    s[jo] = __expf(s[jo] - m);
    sum += s[jo];
  }
  const float inv = 1.f / sum;

  float o[16];
#pragma unroll
  for (int dd = 0; dd < 16; ++dd) o[dd] = 0.f;
#pragma unroll
  for (int jo = 0; jo < 17; ++jo) {
    const float* vr = &Vs[(qi + jo) * 68 + (dg << 4)];
    const float w = s[jo];
#pragma unroll
    for (int c = 0; c < 4; ++c) {
      float4 vv = *(const float4*)(vr + (c << 2));
      o[c * 4 + 0] += w * vv.x; o[c * 4 + 1] += w * vv.y;
      o[c * 4 + 2] += w * vv.z; o[c * 4 + 3] += w * vv.w;
    }
  }

  ushort_t* op = aout + (rowbase + i) * 1024 + (h << 6) + (dg << 4);
  uint4 w0, w1;
  w0.x = packbf2(o[0] * inv, o[1] * inv);
  w0.y = packbf2(o[2] * inv, o[3] * inv);
  w0.z = packbf2(o[4] * inv, o[5] * inv);
  w0.w = packbf2(o[6] * inv, o[7] * inv);
  w1.x = packbf2(o[8] * inv, o[9] * inv);
  w1.y = packbf2(o[10] * inv, o[11] * inv);
  w1.z = packbf2(o[12] * inv, o[13] * inv);
  w1.w = packbf2(o[14] * inv, o[15] * inv);
  *(uint4*)op = w0;
  *(uint4*)(op + 8) = w1;
}

// ---------- launch ----------
extern "C" void kernel_launch(void* const* d_in, const int* in_sizes, int n_in,
                              void* d_out, int out_size, void* d_ws, size_t ws_size,
                              hipStream_t stream) {
  const float* x = (const float*)d_in[0];
  const float* Wqkv = (const float*)d_in[1];
  const float* Wproj = (const float*)d_in[2];
  const float* bproj = (const float*)d_in[3];
  float* out = (float*)d_out;

  char* ws = (char*)d_ws;
  ushort_t* xb    = (ushort_t*)(ws);
  ushort_t* wqkvT = (ushort_t*)(ws + (8u << 20));
  ushort_t* wprT  = (ushort_t*)(ws + (14u << 20));
  ushort_t* qkv   = (ushort_t*)(ws + (16u << 20));
  ushort_t* aoutb = (ushort_t*)(ws + (40u << 20));

  prep_inputs<<<8192, 256, 0, stream>>>(x, xb, Wqkv, wqkvT, Wproj, wprT);
  // QKV: 128x128 tile, grid 24x32 = 768 blocks (3/CU), XCD-swizzled
  gemm2p<true, 4, 4><<<dim3(24, 32), 256, 0, stream>>>(
      xb, wqkvT, qkv, nullptr, 4096, 3072, 1024);
  attn_band<<<dim3(32, 16, 2), 256, 0, stream>>>(qkv, aoutb);
  // proj: 64x128 tile, grid 8x64 = 512 blocks (2/CU), XCD-swizzled
  gemm2p<false, 2, 4><<<dim3(8, 64), 256, 0, stream>>>(
      aoutb, wprT, out, bproj, 4096, 1024, 1024);
}